// Round 2
// baseline (303.493 us; speedup 1.0000x reference)
//
#include <hip/hip_runtime.h>
#include <hip/hip_bf16.h>

// Problem constants
#define S_LEN 2048
#define HID   4096
#define NH    32
#define NKV   8
#define DH    128
#define NQKV  ((NH + 2*NKV) * DH)   // 6144

typedef __attribute__((ext_vector_type(8))) short s16x8;
typedef __attribute__((ext_vector_type(4))) short s16x4;
typedef __attribute__((ext_vector_type(4))) float f32x4;

__device__ __forceinline__ short f2bf(float x) {
    union { __hip_bfloat16 b; short s; } u;
    u.b = __float2bfloat16(x);
    return u.s;
}
__device__ __forceinline__ float bf2f(short s) {
    union { unsigned int u; float f; } v;
    v.u = ((unsigned int)(unsigned short)s) << 16;
    return v.f;
}

// async global->LDS, 16B per lane; lds dest = wave-uniform base + lane*16
__device__ __forceinline__ void gload16(const void* g, void* l) {
    __builtin_amdgcn_global_load_lds(
        (const __attribute__((address_space(1))) void*)g,
        (__attribute__((address_space(3))) void*)l,
        16, 0, 0);
}

__device__ __forceinline__ void cstore(float* p, float v) { *p = v; }
__device__ __forceinline__ void cstore(short* p, float v) { *p = f2bf(v); }

// ---------------------------------------------------------------------------
// fused f32 -> bf16 conversion of hs AND wqkv in one launch
// ---------------------------------------------------------------------------
__global__ __launch_bounds__(256) void convert_hs_wqkv(
        const float* __restrict__ in1, short* __restrict__ o1, long n1,
        const float* __restrict__ in2, short* __restrict__ o2, long n2)
{
    const long total = n1 + n2;
    long i0 = ((long)blockIdx.x * blockDim.x + threadIdx.x) * 4;
    long stride = (long)gridDim.x * blockDim.x * 4;
    for (long i = i0; i < total; i += stride) {
        const float* src; short* dst; long off;
        if (i < n1) { src = in1; dst = o1; off = i; }
        else        { src = in2; dst = o2; off = i - n1; }
        float4 v = *(const float4*)(src + off);
        s16x4 o;
        o[0] = f2bf(v.x); o[1] = f2bf(v.y); o[2] = f2bf(v.z); o[3] = f2bf(v.w);
        *(s16x4*)(dst + off) = o;
    }
}

// ---------------------------------------------------------------------------
// gemm1: 128x192-tile bf16 GEMM, C = A * B^T.  Round-2 rework:
//   - 256 threads (4 waves, 2Mx2N grid, 64x96 per wave), 80KB LDS
//     -> 2 blocks/CU (grid 32x16 = 512).  R1 post-mortem: with 1 block/CU,
//     ~45% of cycles had NEITHER pipe issuing (barrier/waitcnt stalls the
//     whole CU).  Two independent blocks interleave: one block's sync/stage
//     phase overlaps the other's MFMA (m114 implicit overlap; attn kernel
//     proves 2x80KB/CU on this chip).
//   - ONE barrier per K-tile (merged): lgkmcnt(0)+vmcnt(0) -> s_barrier
//     publishes both "slot t reads done" and "tile t+1 resident".
//   - counted lgkmcnt(6): A(read-ahead) + b0 drained, b1 drains under M0.
//   - A-frags double-buffered in regs (read-ahead t+1 under M1); B-frags
//     single-buffered.  ~112 frag VGPRs + 96 acc -> fits 256 @ 2 waves/SIMD.
// per wave/K-tile: 48 MFMA, 20 ds_read_b128; per CU: 384 MFMA, 160KB LDS rd.
// ---------------------------------------------------------------------------
template <typename OT>
__global__ __launch_bounds__(256, 2) void gemm192(
        const short* __restrict__ A, const short* __restrict__ B,
        OT* __restrict__ C, int M, int N, int K)
{
    __shared__ char lds[81920];   // A: 2 x 16KB at [0,32K); B: 2 x 24KB at [32K,80K)
    const int t = threadIdx.x;
    const int w = t >> 6, l = t & 63, g = l >> 4, q16 = l & 15;
    const int wm = w >> 1, wn = w & 1;       // wave grid 2(M) x 2(N)
    const int bx = blockIdx.x, by = blockIdx.y;
    const int NT = K >> 6;                   // 64 at K=4096 (even)

    // staging global byte offsets (chunk pre-swizzled), u32 (buffers < 4GB)
    const int srow = t >> 3;                 // 0..31 within a 32-row band
    const int schunk = (t & 7) ^ (srow & 7); // row&7 == (t>>3)&7 (bands are x32)
    unsigned goffA[4], goffB[6];
#pragma unroll
    for (int i = 0; i < 4; ++i)
        goffA[i] = (unsigned)(((by * 128 + i * 32 + srow) * K) * 2 + schunk * 16);
#pragma unroll
    for (int i = 0; i < 6; ++i)
        goffB[i] = (unsigned)(((bx * 192 + i * 32 + srow) * K) * 2 + schunk * 16);
    const int dstw = w * 1024;               // wave-uniform LDS dest part

    auto STAGE = [&](int kt) {               // 10 DMA instrs: A 16KB + B 24KB
        const int par = kt & 1;
        char* dA = lds + par * 16384 + dstw;
        char* dB = lds + 32768 + par * 24576 + dstw;
        const unsigned kb = (unsigned)kt * 128;   // kt*64 elems * 2B
#pragma unroll
        for (int i = 0; i < 4; ++i)
            gload16((const char*)A + (goffA[i] + kb), dA + i * 4096);
#pragma unroll
        for (int i = 0; i < 6; ++i)
            gload16((const char*)B + (goffB[i] + kb), dB + i * 4096);
    };

    // LDS read offsets (row&7 == q16&7: 64,96,16 all multiples of 8... 16 ok)
    int aoff[4], boff[6];
#pragma unroll
    for (int mi = 0; mi < 4; ++mi) aoff[mi] = (wm * 64 + mi * 16 + q16) * 128;
#pragma unroll
    for (int ni = 0; ni < 6; ++ni) boff[ni] = (wn * 96 + ni * 16 + q16) * 128;
    const int sw0 = ((g) ^ (q16 & 7)) << 4;
    const int sw1 = ((4 + g) ^ (q16 & 7)) << 4;

    f32x4 acc[4][6] = {};
    s16x8 aE[4][2], aO[4][2], b0f[3][2], b1f[3][2];

    // prologue: stage tiles 0,1; publish tile0; read-ahead A(0) -> aE
    STAGE(0); STAGE(1);
    asm volatile("s_waitcnt vmcnt(10)" ::: "memory");
    __builtin_amdgcn_s_barrier();
    {
        const char* A0 = lds;
#pragma unroll
        for (int mi = 0; mi < 4; ++mi) {
            aE[mi][0] = *(const s16x8*)(A0 + aoff[mi] + sw0);
            aE[mi][1] = *(const s16x8*)(A0 + aoff[mi] + sw1);
        }
    }

#define GB(KT, AC, AN, PAR) do {                                              \
    const char* Bs_ = lds + 32768 + (PAR) * 24576;                            \
    _Pragma("unroll")                                                         \
    for (int ni = 0; ni < 3; ++ni) {                                          \
        b0f[ni][0] = *(const s16x8*)(Bs_ + boff[ni] + sw0);                   \
        b0f[ni][1] = *(const s16x8*)(Bs_ + boff[ni] + sw1);                   \
    }                                                                         \
    _Pragma("unroll")                                                         \
    for (int ni = 0; ni < 3; ++ni) {                                          \
        b1f[ni][0] = *(const s16x8*)(Bs_ + boff[3 + ni] + sw0);               \
        b1f[ni][1] = *(const s16x8*)(Bs_ + boff[3 + ni] + sw1);               \
    }                                                                         \
    asm volatile("s_waitcnt lgkmcnt(6)" ::: "memory");  /* A + b0 done */     \
    __builtin_amdgcn_sched_barrier(0);                                        \
    __builtin_amdgcn_s_setprio(1);                                            \
    _Pragma("unroll")                                                         \
    for (int mi = 0; mi < 4; ++mi)                                            \
    _Pragma("unroll")                                                         \
    for (int ni = 0; ni < 3; ++ni)                                            \
    _Pragma("unroll")                                                         \
    for (int kk = 0; kk < 2; ++kk)                                            \
        acc[mi][ni] = __builtin_amdgcn_mfma_f32_16x16x32_bf16(                \
                AC[mi][kk], b0f[ni][kk], acc[mi][ni], 0, 0, 0);               \
    __builtin_amdgcn_s_setprio(0);                                            \
    asm volatile("s_waitcnt lgkmcnt(0)" ::: "memory");  /* b1 done */         \
    __builtin_amdgcn_sched_barrier(0);                                        \
    asm volatile("s_waitcnt vmcnt(0)" ::: "memory");    /* t+1 resident */    \
    __builtin_amdgcn_s_barrier();   /* slot t free + tile t+1 published */    \
    if ((KT) + 2 < NT) STAGE((KT) + 2);                                       \
    if ((KT) + 1 < NT) {            /* read-ahead A(t+1) under M1 */          \
        const char* An_ = lds + (((PAR) ^ 1) * 16384);                        \
        _Pragma("unroll")                                                     \
        for (int mi = 0; mi < 4; ++mi) {                                      \
            AN[mi][0] = *(const s16x8*)(An_ + aoff[mi] + sw0);                \
            AN[mi][1] = *(const s16x8*)(An_ + aoff[mi] + sw1);                \
        }                                                                     \
    }                                                                         \
    __builtin_amdgcn_s_setprio(1);                                            \
    _Pragma("unroll")                                                         \
    for (int mi = 0; mi < 4; ++mi)                                            \
    _Pragma("unroll")                                                         \
    for (int ni = 0; ni < 3; ++ni)                                            \
    _Pragma("unroll")                                                         \
    for (int kk = 0; kk < 2; ++kk)                                            \
        acc[mi][3 + ni] = __builtin_amdgcn_mfma_f32_16x16x32_bf16(            \
                AC[mi][kk], b1f[ni][kk], acc[mi][3 + ni], 0, 0, 0);           \
    __builtin_amdgcn_s_setprio(0);                                            \
} while (0)

    for (int kt = 0; kt < NT; kt += 2) {
        GB(kt,     aE, aO, 0);
        GB(kt + 1, aO, aE, 1);
    }
#undef GB

    // epilogue: D col = lane&15, row = (lane>>4)*4 + r
#pragma unroll
    for (int mi = 0; mi < 4; ++mi) {
        long row = (long)by * 128 + wm * 64 + mi * 16 + g * 4;
#pragma unroll
        for (int ni = 0; ni < 6; ++ni) {
            long col = (long)bx * 192 + wn * 96 + ni * 16 + q16;
            f32x4 v = acc[mi][ni];
#pragma unroll
            for (int r = 0; r < 4; ++r)
                cstore(&C[(row + r) * (long)N + col], v[r]);
        }
    }
}

// ---------------------------------------------------------------------------
// bf16 GEMM (2-phase, proven 920 TF), C[M][N] = A[M][K] * B[N][K]^T.
// 128x128 tile, BK=64, 512 threads (8 waves, 2Mx4N), 64x32 per wave.
// 2-D grid. Used for gemm2 (32x16 = 512 blocks = 2/CU).
// ---------------------------------------------------------------------------
template <typename OT>
__global__ __launch_bounds__(512, 4) void gemm_bt(
        const short* __restrict__ A, const short* __restrict__ B,
        OT* __restrict__ C, int M, int N, int K)
{
    __shared__ char lds[64 * 1024];
    // A bufs: [0,16K) [16K,32K); B bufs: [32K,48K) [48K,64K)
    const int t = threadIdx.x;
    const int w = t >> 6, l = t & 63, g = l >> 4, q16 = l & 15;
    const int wm = w >> 2, wn = w & 3;     // wave grid 2 (M) x 4 (N)
    const long rowA = (long)blockIdx.y * 128;
    const long rowB = (long)blockIdx.x * 128;
    const int NT = K >> 6;

    // precomputed global byte offsets for staging (chunk pre-swizzled)
    long goffA[2], goffB[2];
#pragma unroll
    for (int i = 0; i < 2; ++i) {
        int li = i * 512 + t;
        int row = li >> 3;                       // 0..127
        int chunk = (t & 7) ^ (row & 7);         // swizzled 16B chunk in row
        goffA[i] = ((rowA + row) * (long)K) * 2 + chunk * 16;
        goffB[i] = ((rowB + row) * (long)K) * 2 + chunk * 16;
    }
    const int ldsoff = w * 1024;                 // wave-uniform dest base part

    // precomputed LDS read offsets (swizzled)
    int aoff[4][2], boff[2][2];
#pragma unroll
    for (int m = 0; m < 4; ++m)
#pragma unroll
        for (int k = 0; k < 2; ++k) {
            int row = wm * 64 + m * 16 + q16;
            int chunk = (k * 4 + g) ^ (row & 7);
            aoff[m][k] = row * 128 + chunk * 16;
        }
#pragma unroll
    for (int n = 0; n < 2; ++n)
#pragma unroll
        for (int k = 0; k < 2; ++k) {
            int row = wn * 32 + n * 16 + q16;
            int chunk = (k * 4 + g) ^ (row & 7);
            boff[n][k] = row * 128 + chunk * 16;
        }

    auto STAGE = [&](int kt, char* dA, char* dB) {
        const long kb = (long)kt * 128;          // kt*64 elems * 2B
#pragma unroll
        for (int i = 0; i < 2; ++i)
            gload16((const char*)A + goffA[i] + kb, dA + i * 8192 + ldsoff);
#pragma unroll
        for (int i = 0; i < 2; ++i)
            gload16((const char*)B + goffB[i] + kb, dB + i * 8192 + ldsoff);
    };

    f32x4 acc[4][2] = {};

    STAGE(0, lds, lds + 32768);
    STAGE(1, lds + 16384, lds + 49152);

    for (int kt = 0; kt < NT; ++kt) {
        const int b = kt & 1;
        char* bA = lds + (b ? 16384 : 0);
        char* bB = lds + (b ? 49152 : 32768);
        // tile kt's 4 loads are the oldest; tile kt+1's 4 may stay in flight
        if (kt + 1 < NT) asm volatile("s_waitcnt vmcnt(4)" ::: "memory");
        else             asm volatile("s_waitcnt vmcnt(0)" ::: "memory");
        __builtin_amdgcn_s_barrier();

        s16x8 af[4][2], bfr[2][2];
#pragma unroll
        for (int m = 0; m < 4; ++m)
#pragma unroll
            for (int k = 0; k < 2; ++k)
                af[m][k] = *(const s16x8*)(bA + aoff[m][k]);
#pragma unroll
        for (int n = 0; n < 2; ++n)
#pragma unroll
            for (int k = 0; k < 2; ++k)
                bfr[n][k] = *(const s16x8*)(bB + boff[n][k]);

        __builtin_amdgcn_s_setprio(1);
#pragma unroll
        for (int m = 0; m < 4; ++m)
#pragma unroll
            for (int n = 0; n < 2; ++n)
#pragma unroll
                for (int k = 0; k < 2; ++k)
                    acc[m][n] = __builtin_amdgcn_mfma_f32_16x16x32_bf16(
                            af[m][k], bfr[n][k], acc[m][n], 0, 0, 0);
        __builtin_amdgcn_s_setprio(0);
        __builtin_amdgcn_s_barrier();   // all waves' reads of buf b complete

        if (kt + 2 < NT) STAGE(kt + 2, bA, bB);
    }

    // epilogue: D col = lane&15, row = (lane>>4)*4 + r
#pragma unroll
    for (int m = 0; m < 4; ++m) {
        long row = rowA + wm * 64 + m * 16 + g * 4;
#pragma unroll
        for (int n = 0; n < 2; ++n) {
            long col = rowB + wn * 32 + n * 16 + q16;
            f32x4 v = acc[m][n];
#pragma unroll
            for (int r = 0; r < 4; ++r)
                cstore(&C[(row + r) * (long)N + col], v[r]);
        }
    }
}

// ---------------------------------------------------------------------------
// Fused post-gemm1 kernel: ONE launch doing three independent jobs:
//   blocks [0, 2048):        wo f32->bf16 convert (grid-stride)
//   blocks [2048, 12288):    RMSNorm+RoPE
//   blocks [12288, 12800):   V transpose
// ---------------------------------------------------------------------------
__global__ __launch_bounds__(256) void post_gemm1_fused(
        const float* __restrict__ wo, short* __restrict__ wob,
        const short* __restrict__ qkvb, const int* __restrict__ pos,
        const float* __restrict__ gq, const float* __restrict__ gk,
        short* __restrict__ qo, short* __restrict__ ko,
        short* __restrict__ vt)
{
    const int bid = blockIdx.x;

    if (bid < 2048) {
        // ---- wo f32 -> bf16 convert ----
        const long n = (long)HID * (NH * DH);
        long i0 = ((long)bid * 256 + threadIdx.x) * 4;
        long stride = 2048L * 256 * 4;
        for (long i = i0; i < n; i += stride) {
            float4 v = *(const float4*)(wo + i);
            s16x4 o;
            o[0] = f2bf(v.x); o[1] = f2bf(v.y); o[2] = f2bf(v.z); o[3] = f2bf(v.w);
            *(s16x4*)(wob + i) = o;
        }
        return;
    }

    if (bid < 12288) {
        // ---- RMSNorm + RoPE ----
        const int idx = bid - 2048;
        const int s = idx / 5;
        const int slot = (idx % 5) * 8 + (threadIdx.x >> 5);   // 0..39
        const int p = threadIdx.x & 31, d = p * 4;

        s16x4 xv = *(const s16x4*)(qkvb + (long)s * NQKV + slot * DH + d);
        float x[4];
#pragma unroll
        for (int r = 0; r < 4; ++r) x[r] = bf2f(xv[r]);

        float ss = x[0]*x[0] + x[1]*x[1] + x[2]*x[2] + x[3]*x[3];
#pragma unroll
        for (int o = 1; o < 32; o <<= 1) ss += __shfl_xor(ss, o);
        float rms = rsqrtf(ss * (1.0f / DH) + 1e-6f);

        const bool isq = slot < NH;
        const float* gp = isq ? gq : gk;
        float y[4];
#pragma unroll
        for (int r = 0; r < 4; ++r) y[r] = x[r] * rms * gp[d + r];

        float y2[4];
#pragma unroll
        for (int r = 0; r < 4; ++r) y2[r] = __shfl_xor(y[r], 16);

        const float po = (float)pos[s];
        const int jbase = d & 63;
        s16x4 ov;
#pragma unroll
        for (int r = 0; r < 4; ++r) {
            float invf = exp2f(-(float)(jbase + r) * (13.287712379549449f / 64.0f));
            float ang = po * invf;
            float c = cosf(ang), sn = sinf(ang);
            float outv = (d < 64) ? (y[r] * c - y2[r] * sn)
                                  : (y[r] * c + y2[r] * sn);
            ov[r] = f2bf(outv);
        }
        if (isq) *(s16x4*)(qo + ((long)s * NH + slot) * DH + d) = ov;
        else     *(s16x4*)(ko + ((long)s * NKV + (slot - NH)) * DH + d) = ov;
        return;
    }

    // ---- V transpose: qkvb v-slots -> vt[h][d][s], 64x64 LDS tiles ----
    __shared__ short tile[64][72];
    const int idx2 = bid - 12288;
    const int sb = idx2 & 31, db = (idx2 >> 5) & 1, h = idx2 >> 6;
    const int t = threadIdx.x;
#pragma unroll
    for (int i = 0; i < 2; ++i) {
        int c = i * 256 + t;
        int row = c >> 3, dc = (c & 7) * 8;
        const short* src = qkvb + (long)(sb*64 + row) * NQKV
                           + (NH + NKV + h) * DH + db*64 + dc;
        s16x8 x = *(const s16x8*)src;
#pragma unroll
        for (int jj = 0; jj < 8; ++jj) tile[row][dc + jj] = x[jj];
    }
    __syncthreads();
#pragma unroll
    for (int i = 0; i < 2; ++i) {
        int c = i * 256 + t;
        int dr = c >> 3, sc = (c & 7) * 8;
        s16x8 y;
#pragma unroll
        for (int jj = 0; jj < 8; ++jj) y[jj] = tile[sc + jj][dr];
        short* dst = vt + (long)(h*DH + db*64 + dr) * S_LEN + sb*64 + sc;
        *(s16x8*)dst = y;
    }
}

// ---------------------------------------------------------------------------
// stage one K tile [64][128] and one Vt tile [128][64] into LDS via
// global_load_lds, PRE-SWIZZLED global source (+ linear LDS dest).
// V staging is PREFETCH (fire-and-forget DMA a tile ahead) — r18's
// V-from-global inline gather was 3x slower (latency-serialized).
// ---------------------------------------------------------------------------
__device__ __forceinline__ void stage_kv(const char* kgB, const char* vgB,
                                         int kt, int t, char* kd, char* vd)
{
    const int w = t >> 6;
#pragma unroll
    for (int ci = 0; ci < 4; ++ci) {
        int c = ci * 256 + t;
        int row = c >> 4, col16 = c & 15;
        const char* gk = kgB + (long)(kt*64 + row) * (NKV*DH*2)
                         + ((col16*16) ^ ((row & 7) << 4));
        gload16(gk, kd + ci*4096 + w*1024);
        int rowv = c >> 3, scol8 = c & 7;
        const char* gv = vgB + (long)rowv * (S_LEN*2) + kt*128
                         + ((scol8*16) ^ ((rowv & 7) << 4));
        gload16(gv, vd + ci*4096 + w*1024);
    }
}

// ---------------------------------------------------------------------------
// Causal GQA flash attention, v12 (round-8 math, co-residency grid) — the
// best-measured variant (r14/r16/r17). r18's V-from-global reverted.
// ---------------------------------------------------------------------------
__global__ __launch_bounds__(256, 2) void attn_kernel(
        const short* __restrict__ qg, const short* __restrict__ kg,
        const short* __restrict__ vtg, short* __restrict__ ctx)
{
    const int bx = blockIdx.x;       // 0..511
    const int h  = bx & 31;          // head
    const int slot = bx >> 5;        // 0..15
    const int qb = (slot < 8) ? slot : 23 - slot;   // complementary pairing
    const int kvh = h >> 2;          // GQA: rep=4
    const int t = threadIdx.x, w = t >> 6, l = t & 63, g = l >> 4, q16 = l & 15;

    __shared__ char Kl[2][16384];    // [kv64][d128] bf16, swizzled
    __shared__ char Vl[2][16384];    // [d128][kv64] bf16, swizzled
    __shared__ short Pl[4][32 * 64]; // per-wave P[32 q][64 kv], swizzled

    const float scale = 0.08838834764831845f;  // 1/sqrt(128)
    const char* kgB = (const char*)kg + (long)kvh * DH * 2;
    const char* vgB = (const char*)vtg + (long)kvh * DH * (long)S_LEN * 2;

    const int nt = 2 * qb + 2;               // kv-tiles of 64
    int qrow[2];
    qrow[0] = qb*128 + w*32 + q16;
    qrow[1] = qrow[0] + 16;

    // Q B-frags for both subtiles (regs for whole block)
    s16x8 qf[2][4];
#pragma unroll
    for (int s = 0; s < 2; ++s) {
        const short* qptr = qg + ((long)qrow[s] * NH + h) * DH;
#pragma unroll
        for (int dk = 0; dk < 4; ++dk)
            qf[s][dk] = *(const s16x8*)(qptr + dk*32 + g*8);
    }

    f32x4 oacc[2][8] = {};
    float m_run[2] = {-1e30f, -1e30f}, l_run[2] = {0.f, 0.f};

    stage_kv(kgB, vgB, 0, t, Kl[0], Vl[0]);
    __syncthreads();   // drain vmcnt -> buf0 ready

    for (int kt = 0; kt < nt; ++kt) {
        const int b = kt & 1;
        if (kt + 1 < nt)   // prefetch next tile into other buffer (async)
            stage_kv(kgB, vgB, kt + 1, t, Kl[b ^ 1], Vl[b ^ 1]);
        const char* kb = Kl[b];
        const char* vbb = Vl[b];

        // ---- QK^T swapped: S^T[kv][q] = K * Q^T; K-frags serve both s
        f32x4 sacc[2][4] = {};
        __builtin_amdgcn_s_setprio(1);
#pragma unroll
        for (int m = 0; m < 4; ++m) {
            int kvr = m*16 + q16;
            s16x8 af[4];
#pragma unroll
            for (int dk = 0; dk < 4; ++dk) {
                int byte = (kvr*256 + (dk*32 + g*8)*2) ^ ((kvr & 7) << 4);
                af[dk] = *(const s16x8*)(kb + byte);
            }
#pragma unroll
            for (int s = 0; s < 2; ++s)
#pragma unroll
                for (int dk = 0; dk < 4; ++dk)
                    sacc[s][m] = __builtin_amdgcn_mfma_f32_16x16x32_bf16(
                            af[dk], qf[s][dk], sacc[s][m], 0,0,0);
        }
        __builtin_amdgcn_s_setprio(0);

        // ---- online softmax; lane owns q-columns qrow[0], qrow[1] ----
        const bool diag = (kt >= 2*qb);      // last two tiles straddle diag
        float mx[2];
#pragma unroll
        for (int s = 0; s < 2; ++s) {
            mx[s] = -1e30f;
#pragma unroll
            for (int m = 0; m < 4; ++m)
#pragma unroll
                for (int r = 0; r < 4; ++r) {
                    float x = sacc[s][m][r] * scale;
                    if (diag) {
                        int kv = kt*64 + m*16 + g*4 + r;
                        if (kv > qrow[s]) x = -1e30f;
                    }
                    sacc[s][m][r] = x;
                    mx[s] = fmaxf(mx[s], x);
                }
            mx[s] = fmaxf(mx[s], __shfl_xor(mx[s], 16));
            mx[s] = fmaxf(mx[s], __shfl_xor(mx[s], 32));
        }
        // defer-max: only rescale when max grew by > 8 somewhere (T13)
        if (__any((mx[0] > m_run[0] + 8.f) || (mx[1] > m_run[1] + 8.f))) {
#pragma unroll
            for (int s = 0; s < 2; ++s) {
                float m_new = fmaxf(m_run[s], mx[s]);
                float corr = __expf(m_run[s] - m_new);
                l_run[s] *= corr;
                m_run[s] = m_new;
                float rf[4];
#pragma unroll
                for (int r = 0; r < 4; ++r)
                    rf[r] = __shfl(corr, (g << 4) | (g*4 + r));
#pragma unroll
                for (int nf = 0; nf < 8; ++nf)
#pragma unroll
                    for (int r = 0; r < 4; ++r) oacc[s][nf][r] *= rf[r];
            }
        }
        // exp + pack to bf16 + LDS write (P bounded by e^8 when deferred)
#pragma unroll
        for (int s = 0; s < 2; ++s) {
            float psum = 0.f;
#pragma unroll
            for (int m = 0; m < 4; ++m) {
                s16x4 pk;
#pragma unroll
                for (int r = 0; r < 4; ++r) {
                    float e = __expf(sacc[s][m][r] - m_run[s]);
                    psum += e;
                    pk[r] = f2bf(e);
                }
                int byte = ((s*16 + q16)*128 + (m*16 + g*4)*2) ^ ((q16 & 7) << 4);
                *(s16x4*)((char*)&Pl[w][0] + byte) = pk;
            }
            psum += __shfl_xor(psum, 16);
            psum += __shfl_xor(psum, 32);
            l_run[s] += psum;
        }

        // ---- PV: O[q][d] += P[q][kv] * V[kv][d]; V-frags serve both s
        __builtin_amdgcn_s_setprio(1);
#pragma unroll
        for (int ks = 0; ks < 2; ++ks) {
            s16x8 pa[2];
#pragma unroll
            for (int s = 0; s < 2; ++s) {
                int pbyte = ((s*16 + q16)*128 + (ks*32 + g*8)*2) ^ ((q16 & 7) << 4);
                pa[s] = *(const s16x8*)((const char*)&Pl[w][0] + pbyte);
            }
#pragma unroll
            for (int nf = 0; nf < 8; ++nf) {
                int drow = nf*16 + q16;
                int vbyte = (drow*128 + (ks*32 + g*8)*2) ^ ((drow & 7) << 4);
                s16x8 vbf = *(const s16x8*)(vbb + vbyte);
#pragma unroll
                for (int s = 0; s < 2; ++s)
                    oacc[s][nf] = __builtin_amdgcn_mfma_f32_16x16x32_bf16(
                            pa[s], vbf, oacc[s][nf], 0,0,0);
            }
        }
        __builtin_amdgcn_s_setprio(0);
        __syncthreads();   // tile done; prefetched buffer complete
    }

    // ---- epilogue: divide by l, write ctx[row][h*128 + d] bf16 ----
#pragma unroll
    for (int s = 0; s < 2; ++s) {
        float lr[4];
#pragma unroll
        for (int r = 0; r < 4; ++r)
            lr[r] = __shfl(l_run[s], (g << 4) | (g*4 + r));
#pragma unroll
        for (int nf = 0; nf < 8; ++nf)
#pragma unroll
            for (int r = 0; r < 4; ++r) {
                int row = qb*128 + w*32 + s*16 + g*4 + r;
                int col = h*DH + nf*16 + q16;
                float val = oacc[s][nf][r] / lr[r];
                ctx[(long)row * (NH*DH) + col] = f2bf(val);
            }
    }
}

// ---------------------------------------------------------------------------
// Workspace layout (race-free, peak 111 MB):
//   [0,16)    hsb (gemm1 A)           -> ctxb (attn out) after gemm1
//   [16,67)   wqkvb (gemm1 B, 50.3MB) -> wob (32MB) after gemm1
//   [48,52)   vtbuf (4MB, written after gemm1)
//   [67,91)   qkvb (gemm1 bf16 out, 24MB)
//   [91,107)  qbuf (16MB)
//   [107,111) kbuf (4MB)
// ---------------------------------------------------------------------------
extern "C" void kernel_launch(void* const* d_in, const int* in_sizes, int n_in,
                              void* d_out, int out_size, void* d_ws, size_t ws_size,
                              hipStream_t stream)
{
    const int*   positions = (const int*)  d_in[0];
    const float* hs        = (const float*)d_in[1];
    const float* wqkv      = (const float*)d_in[2];
    const float* wo        = (const float*)d_in[3];
    const float* gq        = (const float*)d_in[4];
    const float* gk        = (const float*)d_in[5];
    float* out = (float*)d_out;
    char* ws = (char*)d_ws;

    const size_t MB = 1ull << 20;
    short* hsb   = (short*)(ws);
    short* ctxb  = (short*)(ws);
    short* wqkvb = (short*)(ws + 16*MB);
    short* wob   = (short*)(ws + 16*MB);
    short* vtbuf = (short*)(ws + 48*MB);
    short* qkvb  = (short*)(ws + 67*MB);
    short* qbuf  = (short*)(ws + 91*MB);
    short* kbuf  = (short*)(ws + 107*MB);

    (void)in_sizes; (void)n_in; (void)out_size; (void)ws_size;

    convert_hs_wqkv<<<2048, 256, 0, stream>>>(
            hs, hsb, (long)S_LEN * HID,
            wqkv, wqkvb, (long)NQKV * HID);
    gemm192<short><<<dim3(NQKV/192, S_LEN/128), 256, 0, stream>>>(
            hsb, wqkvb, qkvb, S_LEN, NQKV, HID);
    post_gemm1_fused<<<12800, 256, 0, stream>>>(
            wo, wob, qkvb, positions, gq, gk, qbuf, kbuf, vtbuf);
    attn_kernel<<<dim3(512), 256, 0, stream>>>(qbuf, kbuf, vtbuf, ctxb);
    gemm_bt<float><<<dim3(HID/128, S_LEN/128), 512, 0, stream>>>(
            ctxb, wob, out, S_LEN, HID, HID);
}

// Round 3
// 302.061 us; speedup vs baseline: 1.0047x; 1.0047x over previous
//
#include <hip/hip_runtime.h>
#include <hip/hip_bf16.h>

// Problem constants
#define S_LEN 2048
#define HID   4096
#define NH    32
#define NKV   8
#define DH    128
#define NQKV  ((NH + 2*NKV) * DH)   // 6144

typedef __attribute__((ext_vector_type(8))) short s16x8;
typedef __attribute__((ext_vector_type(4))) short s16x4;
typedef __attribute__((ext_vector_type(4))) float f32x4;

__device__ __forceinline__ short f2bf(float x) {
    union { __hip_bfloat16 b; short s; } u;
    u.b = __float2bfloat16(x);
    return u.s;
}
__device__ __forceinline__ float bf2f(short s) {
    union { unsigned int u; float f; } v;
    v.u = ((unsigned int)(unsigned short)s) << 16;
    return v.f;
}

// async global->LDS, 16B per lane; lds dest = wave-uniform base + lane*16
__device__ __forceinline__ void gload16(const void* g, void* l) {
    __builtin_amdgcn_global_load_lds(
        (const __attribute__((address_space(1))) void*)g,
        (__attribute__((address_space(3))) void*)l,
        16, 0, 0);
}

__device__ __forceinline__ void cstore(float* p, float v) { *p = v; }
__device__ __forceinline__ void cstore(short* p, float v) { *p = f2bf(v); }

// ---------------------------------------------------------------------------
// fused f32 -> bf16 conversion of hs AND wqkv in one launch
// ---------------------------------------------------------------------------
__global__ __launch_bounds__(256) void convert_hs_wqkv(
        const float* __restrict__ in1, short* __restrict__ o1, long n1,
        const float* __restrict__ in2, short* __restrict__ o2, long n2)
{
    const long total = n1 + n2;
    long i0 = ((long)blockIdx.x * blockDim.x + threadIdx.x) * 4;
    long stride = (long)gridDim.x * blockDim.x * 4;
    for (long i = i0; i < total; i += stride) {
        const float* src; short* dst; long off;
        if (i < n1) { src = in1; dst = o1; off = i; }
        else        { src = in2; dst = o2; off = i - n1; }
        float4 v = *(const float4*)(src + off);
        s16x4 o;
        o[0] = f2bf(v.x); o[1] = f2bf(v.y); o[2] = f2bf(v.z); o[3] = f2bf(v.w);
        *(s16x4*)(dst + off) = o;
    }
}

// ---------------------------------------------------------------------------
// gemm1: 128x192-tile bf16 GEMM, C = A * B^T.  Round-3: R2 structure +
// ANTI-PHASE STAGGER.  R2 post-mortem: per K-tile, MFMA needs 1862 cyc/SIMD
// and the LDS pipe needs 1920 cyc/CU; measured 3664 = their SUM -> the two
// co-resident blocks run in LOCKSTEP (identical code, identical barrier
// cadence, launched together), so both read-burst then both MFMA-burst.
// Fix: blocks with (by & 8) sleep ~1500 cyc ONCE, after their prefetch DMAs
// are issued (sleep overlaps staging -> free).  Pairing heuristic: block b
// and b+256 co-reside; grid (32,16) -> pair differs by by^=8.  Anti-phase:
// one block's ds_read burst fills LDS pipe while the other's MFMA burst
// fills the matrix pipe.  Floor -> max(1920,1862) ~ 2100 cyc/K-tile.
// ---------------------------------------------------------------------------
template <typename OT>
__global__ __launch_bounds__(256, 2) void gemm192(
        const short* __restrict__ A, const short* __restrict__ B,
        OT* __restrict__ C, int M, int N, int K)
{
    __shared__ char lds[81920];   // A: 2 x 16KB at [0,32K); B: 2 x 24KB at [32K,80K)
    const int t = threadIdx.x;
    const int w = t >> 6, l = t & 63, g = l >> 4, q16 = l & 15;
    const int wm = w >> 1, wn = w & 1;       // wave grid 2(M) x 2(N)
    const int bx = blockIdx.x, by = blockIdx.y;
    const int NT = K >> 6;                   // 64 at K=4096 (even)

    // staging global byte offsets (chunk pre-swizzled), u32 (buffers < 4GB)
    const int srow = t >> 3;                 // 0..31 within a 32-row band
    const int schunk = (t & 7) ^ (srow & 7); // row&7 == (t>>3)&7 (bands are x32)
    unsigned goffA[4], goffB[6];
#pragma unroll
    for (int i = 0; i < 4; ++i)
        goffA[i] = (unsigned)(((by * 128 + i * 32 + srow) * K) * 2 + schunk * 16);
#pragma unroll
    for (int i = 0; i < 6; ++i)
        goffB[i] = (unsigned)(((bx * 192 + i * 32 + srow) * K) * 2 + schunk * 16);
    const int dstw = w * 1024;               // wave-uniform LDS dest part

    auto STAGE = [&](int kt) {               // 10 DMA instrs: A 16KB + B 24KB
        const int par = kt & 1;
        char* dA = lds + par * 16384 + dstw;
        char* dB = lds + 32768 + par * 24576 + dstw;
        const unsigned kb = (unsigned)kt * 128;   // kt*64 elems * 2B
#pragma unroll
        for (int i = 0; i < 4; ++i)
            gload16((const char*)A + (goffA[i] + kb), dA + i * 4096);
#pragma unroll
        for (int i = 0; i < 6; ++i)
            gload16((const char*)B + (goffB[i] + kb), dB + i * 4096);
    };

    // LDS read offsets (row&7 == q16&7: 64,96,16 all multiples of 8... 16 ok)
    int aoff[4], boff[6];
#pragma unroll
    for (int mi = 0; mi < 4; ++mi) aoff[mi] = (wm * 64 + mi * 16 + q16) * 128;
#pragma unroll
    for (int ni = 0; ni < 6; ++ni) boff[ni] = (wn * 96 + ni * 16 + q16) * 128;
    const int sw0 = ((g) ^ (q16 & 7)) << 4;
    const int sw1 = ((4 + g) ^ (q16 & 7)) << 4;

    f32x4 acc[4][6] = {};
    s16x8 aE[4][2], aO[4][2], b0f[3][2], b1f[3][2];

    // prologue: stage tiles 0,1; publish tile0; read-ahead A(0) -> aE
    STAGE(0); STAGE(1);
    // anti-phase stagger: odd co-resident block sleeps ~1536 cyc while its
    // prefetch DMAs fly.  Breaks cross-block lockstep (speed-only heuristic).
    if (by & 8) {
        asm volatile("s_sleep 12" ::: "memory");
        asm volatile("s_sleep 12" ::: "memory");
    }
    asm volatile("s_waitcnt vmcnt(10)" ::: "memory");
    __builtin_amdgcn_s_barrier();
    {
        const char* A0 = lds;
#pragma unroll
        for (int mi = 0; mi < 4; ++mi) {
            aE[mi][0] = *(const s16x8*)(A0 + aoff[mi] + sw0);
            aE[mi][1] = *(const s16x8*)(A0 + aoff[mi] + sw1);
        }
    }

#define GB(KT, AC, AN, PAR) do {                                              \
    const char* Bs_ = lds + 32768 + (PAR) * 24576;                            \
    _Pragma("unroll")                                                         \
    for (int ni = 0; ni < 3; ++ni) {                                          \
        b0f[ni][0] = *(const s16x8*)(Bs_ + boff[ni] + sw0);                   \
        b0f[ni][1] = *(const s16x8*)(Bs_ + boff[ni] + sw1);                   \
    }                                                                         \
    _Pragma("unroll")                                                         \
    for (int ni = 0; ni < 3; ++ni) {                                          \
        b1f[ni][0] = *(const s16x8*)(Bs_ + boff[3 + ni] + sw0);               \
        b1f[ni][1] = *(const s16x8*)(Bs_ + boff[3 + ni] + sw1);               \
    }                                                                         \
    asm volatile("s_waitcnt lgkmcnt(6)" ::: "memory");  /* A + b0 done */     \
    __builtin_amdgcn_sched_barrier(0);                                        \
    __builtin_amdgcn_s_setprio(1);                                            \
    _Pragma("unroll")                                                         \
    for (int mi = 0; mi < 4; ++mi)                                            \
    _Pragma("unroll")                                                         \
    for (int ni = 0; ni < 3; ++ni)                                            \
    _Pragma("unroll")                                                         \
    for (int kk = 0; kk < 2; ++kk)                                            \
        acc[mi][ni] = __builtin_amdgcn_mfma_f32_16x16x32_bf16(                \
                AC[mi][kk], b0f[ni][kk], acc[mi][ni], 0, 0, 0);               \
    __builtin_amdgcn_s_setprio(0);                                            \
    asm volatile("s_waitcnt lgkmcnt(0)" ::: "memory");  /* b1 done */         \
    __builtin_amdgcn_sched_barrier(0);                                        \
    asm volatile("s_waitcnt vmcnt(0)" ::: "memory");    /* t+1 resident */    \
    __builtin_amdgcn_s_barrier();   /* slot t free + tile t+1 published */    \
    if ((KT) + 2 < NT) STAGE((KT) + 2);                                       \
    if ((KT) + 1 < NT) {            /* read-ahead A(t+1) under M1 */          \
        const char* An_ = lds + (((PAR) ^ 1) * 16384);                        \
        _Pragma("unroll")                                                     \
        for (int mi = 0; mi < 4; ++mi) {                                      \
            AN[mi][0] = *(const s16x8*)(An_ + aoff[mi] + sw0);                \
            AN[mi][1] = *(const s16x8*)(An_ + aoff[mi] + sw1);                \
        }                                                                     \
    }                                                                         \
    __builtin_amdgcn_s_setprio(1);                                            \
    _Pragma("unroll")                                                         \
    for (int mi = 0; mi < 4; ++mi)                                            \
    _Pragma("unroll")                                                         \
    for (int ni = 0; ni < 3; ++ni)                                            \
    _Pragma("unroll")                                                         \
    for (int kk = 0; kk < 2; ++kk)                                            \
        acc[mi][3 + ni] = __builtin_amdgcn_mfma_f32_16x16x32_bf16(            \
                AC[mi][kk], b1f[ni][kk], acc[mi][3 + ni], 0, 0, 0);           \
    __builtin_amdgcn_s_setprio(0);                                            \
} while (0)

    for (int kt = 0; kt < NT; kt += 2) {
        GB(kt,     aE, aO, 0);
        GB(kt + 1, aO, aE, 1);
    }
#undef GB

    // epilogue: D col = lane&15, row = (lane>>4)*4 + r
#pragma unroll
    for (int mi = 0; mi < 4; ++mi) {
        long row = (long)by * 128 + wm * 64 + mi * 16 + g * 4;
#pragma unroll
        for (int ni = 0; ni < 6; ++ni) {
            long col = (long)bx * 192 + wn * 96 + ni * 16 + q16;
            f32x4 v = acc[mi][ni];
#pragma unroll
            for (int r = 0; r < 4; ++r)
                cstore(&C[(row + r) * (long)N + col], v[r]);
        }
    }
}

// ---------------------------------------------------------------------------
// bf16 GEMM (2-phase, proven 920 TF), C[M][N] = A[M][K] * B[N][K]^T.
// 128x128 tile, BK=64, 512 threads (8 waves, 2Mx4N), 64x32 per wave.
// 2-D grid. Used for gemm2 (32x16 = 512 blocks = 2/CU).
// R3: same anti-phase stagger as gemm192 (2 blocks/CU, LDS-pipe-bound:
// 192 ds_read x 12cyc = 2304 cyc/K-tile vs 1242 MFMA cyc/SIMD).
// ---------------------------------------------------------------------------
template <typename OT>
__global__ __launch_bounds__(512, 4) void gemm_bt(
        const short* __restrict__ A, const short* __restrict__ B,
        OT* __restrict__ C, int M, int N, int K)
{
    __shared__ char lds[64 * 1024];
    // A bufs: [0,16K) [16K,32K); B bufs: [32K,48K) [48K,64K)
    const int t = threadIdx.x;
    const int w = t >> 6, l = t & 63, g = l >> 4, q16 = l & 15;
    const int wm = w >> 2, wn = w & 3;     // wave grid 2 (M) x 4 (N)
    const long rowA = (long)blockIdx.y * 128;
    const long rowB = (long)blockIdx.x * 128;
    const int NT = K >> 6;

    // precomputed global byte offsets for staging (chunk pre-swizzled)
    long goffA[2], goffB[2];
#pragma unroll
    for (int i = 0; i < 2; ++i) {
        int li = i * 512 + t;
        int row = li >> 3;                       // 0..127
        int chunk = (t & 7) ^ (row & 7);         // swizzled 16B chunk in row
        goffA[i] = ((rowA + row) * (long)K) * 2 + chunk * 16;
        goffB[i] = ((rowB + row) * (long)K) * 2 + chunk * 16;
    }
    const int ldsoff = w * 1024;                 // wave-uniform dest base part

    // precomputed LDS read offsets (swizzled)
    int aoff[4][2], boff[2][2];
#pragma unroll
    for (int m = 0; m < 4; ++m)
#pragma unroll
        for (int k = 0; k < 2; ++k) {
            int row = wm * 64 + m * 16 + q16;
            int chunk = (k * 4 + g) ^ (row & 7);
            aoff[m][k] = row * 128 + chunk * 16;
        }
#pragma unroll
    for (int n = 0; n < 2; ++n)
#pragma unroll
        for (int k = 0; k < 2; ++k) {
            int row = wn * 32 + n * 16 + q16;
            int chunk = (k * 4 + g) ^ (row & 7);
            boff[n][k] = row * 128 + chunk * 16;
        }

    auto STAGE = [&](int kt, char* dA, char* dB) {
        const long kb = (long)kt * 128;          // kt*64 elems * 2B
#pragma unroll
        for (int i = 0; i < 2; ++i)
            gload16((const char*)A + goffA[i] + kb, dA + i * 8192 + ldsoff);
#pragma unroll
        for (int i = 0; i < 2; ++i)
            gload16((const char*)B + goffB[i] + kb, dB + i * 8192 + ldsoff);
    };

    f32x4 acc[4][2] = {};

    STAGE(0, lds, lds + 32768);
    STAGE(1, lds + 16384, lds + 49152);
    // anti-phase stagger (see gemm192): odd co-resident block sleeps ~1400cy
    if (blockIdx.y & 8) {
        asm volatile("s_sleep 11" ::: "memory");
        asm volatile("s_sleep 11" ::: "memory");
    }

    for (int kt = 0; kt < NT; ++kt) {
        const int b = kt & 1;
        char* bA = lds + (b ? 16384 : 0);
        char* bB = lds + (b ? 49152 : 32768);
        // tile kt's 4 loads are the oldest; tile kt+1's 4 may stay in flight
        if (kt + 1 < NT) asm volatile("s_waitcnt vmcnt(4)" ::: "memory");
        else             asm volatile("s_waitcnt vmcnt(0)" ::: "memory");
        __builtin_amdgcn_s_barrier();

        s16x8 af[4][2], bfr[2][2];
#pragma unroll
        for (int m = 0; m < 4; ++m)
#pragma unroll
            for (int k = 0; k < 2; ++k)
                af[m][k] = *(const s16x8*)(bA + aoff[m][k]);
#pragma unroll
        for (int n = 0; n < 2; ++n)
#pragma unroll
            for (int k = 0; k < 2; ++k)
                bfr[n][k] = *(const s16x8*)(bB + boff[n][k]);

        __builtin_amdgcn_s_setprio(1);
#pragma unroll
        for (int m = 0; m < 4; ++m)
#pragma unroll
            for (int n = 0; n < 2; ++n)
#pragma unroll
                for (int k = 0; k < 2; ++k)
                    acc[m][n] = __builtin_amdgcn_mfma_f32_16x16x32_bf16(
                            af[m][k], bfr[n][k], acc[m][n], 0, 0, 0);
        __builtin_amdgcn_s_setprio(0);
        __builtin_amdgcn_s_barrier();   // all waves' reads of buf b complete

        if (kt + 2 < NT) STAGE(kt + 2, bA, bB);
    }

    // epilogue: D col = lane&15, row = (lane>>4)*4 + r
#pragma unroll
    for (int m = 0; m < 4; ++m) {
        long row = rowA + wm * 64 + m * 16 + g * 4;
#pragma unroll
        for (int n = 0; n < 2; ++n) {
            long col = rowB + wn * 32 + n * 16 + q16;
            f32x4 v = acc[m][n];
#pragma unroll
            for (int r = 0; r < 4; ++r)
                cstore(&C[(row + r) * (long)N + col], v[r]);
        }
    }
}

// ---------------------------------------------------------------------------
// Fused post-gemm1 kernel: ONE launch doing three independent jobs:
//   blocks [0, 2048):        wo f32->bf16 convert (grid-stride)
//   blocks [2048, 12288):    RMSNorm+RoPE
//   blocks [12288, 12800):   V transpose
// ---------------------------------------------------------------------------
__global__ __launch_bounds__(256) void post_gemm1_fused(
        const float* __restrict__ wo, short* __restrict__ wob,
        const short* __restrict__ qkvb, const int* __restrict__ pos,
        const float* __restrict__ gq, const float* __restrict__ gk,
        short* __restrict__ qo, short* __restrict__ ko,
        short* __restrict__ vt)
{
    const int bid = blockIdx.x;

    if (bid < 2048) {
        // ---- wo f32 -> bf16 convert ----
        const long n = (long)HID * (NH * DH);
        long i0 = ((long)bid * 256 + threadIdx.x) * 4;
        long stride = 2048L * 256 * 4;
        for (long i = i0; i < n; i += stride) {
            float4 v = *(const float4*)(wo + i);
            s16x4 o;
            o[0] = f2bf(v.x); o[1] = f2bf(v.y); o[2] = f2bf(v.z); o[3] = f2bf(v.w);
            *(s16x4*)(wob + i) = o;
        }
        return;
    }

    if (bid < 12288) {
        // ---- RMSNorm + RoPE ----
        const int idx = bid - 2048;
        const int s = idx / 5;
        const int slot = (idx % 5) * 8 + (threadIdx.x >> 5);   // 0..39
        const int p = threadIdx.x & 31, d = p * 4;

        s16x4 xv = *(const s16x4*)(qkvb + (long)s * NQKV + slot * DH + d);
        float x[4];
#pragma unroll
        for (int r = 0; r < 4; ++r) x[r] = bf2f(xv[r]);

        float ss = x[0]*x[0] + x[1]*x[1] + x[2]*x[2] + x[3]*x[3];
#pragma unroll
        for (int o = 1; o < 32; o <<= 1) ss += __shfl_xor(ss, o);
        float rms = rsqrtf(ss * (1.0f / DH) + 1e-6f);

        const bool isq = slot < NH;
        const float* gp = isq ? gq : gk;
        float y[4];
#pragma unroll
        for (int r = 0; r < 4; ++r) y[r] = x[r] * rms * gp[d + r];

        float y2[4];
#pragma unroll
        for (int r = 0; r < 4; ++r) y2[r] = __shfl_xor(y[r], 16);

        const float po = (float)pos[s];
        const int jbase = d & 63;
        s16x4 ov;
#pragma unroll
        for (int r = 0; r < 4; ++r) {
            float invf = exp2f(-(float)(jbase + r) * (13.287712379549449f / 64.0f));
            float ang = po * invf;
            float c = cosf(ang), sn = sinf(ang);
            float outv = (d < 64) ? (y[r] * c - y2[r] * sn)
                                  : (y[r] * c + y2[r] * sn);
            ov[r] = f2bf(outv);
        }
        if (isq) *(s16x4*)(qo + ((long)s * NH + slot) * DH + d) = ov;
        else     *(s16x4*)(ko + ((long)s * NKV + (slot - NH)) * DH + d) = ov;
        return;
    }

    // ---- V transpose: qkvb v-slots -> vt[h][d][s], 64x64 LDS tiles ----
    __shared__ short tile[64][72];
    const int idx2 = bid - 12288;
    const int sb = idx2 & 31, db = (idx2 >> 5) & 1, h = idx2 >> 6;
    const int t = threadIdx.x;
#pragma unroll
    for (int i = 0; i < 2; ++i) {
        int c = i * 256 + t;
        int row = c >> 3, dc = (c & 7) * 8;
        const short* src = qkvb + (long)(sb*64 + row) * NQKV
                           + (NH + NKV + h) * DH + db*64 + dc;
        s16x8 x = *(const s16x8*)src;
#pragma unroll
        for (int jj = 0; jj < 8; ++jj) tile[row][dc + jj] = x[jj];
    }
    __syncthreads();
#pragma unroll
    for (int i = 0; i < 2; ++i) {
        int c = i * 256 + t;
        int dr = c >> 3, sc = (c & 7) * 8;
        s16x8 y;
#pragma unroll
        for (int jj = 0; jj < 8; ++jj) y[jj] = tile[sc + jj][dr];
        short* dst = vt + (long)(h*DH + db*64 + dr) * S_LEN + sb*64 + sc;
        *(s16x8*)dst = y;
    }
}

// ---------------------------------------------------------------------------
// stage one K tile [64][128] and one Vt tile [128][64] into LDS via
// global_load_lds, PRE-SWIZZLED global source (+ linear LDS dest).
// V staging is PREFETCH (fire-and-forget DMA a tile ahead) — r18's
// V-from-global inline gather was 3x slower (latency-serialized).
// ---------------------------------------------------------------------------
__device__ __forceinline__ void stage_kv(const char* kgB, const char* vgB,
                                         int kt, int t, char* kd, char* vd)
{
    const int w = t >> 6;
#pragma unroll
    for (int ci = 0; ci < 4; ++ci) {
        int c = ci * 256 + t;
        int row = c >> 4, col16 = c & 15;
        const char* gk = kgB + (long)(kt*64 + row) * (NKV*DH*2)
                         + ((col16*16) ^ ((row & 7) << 4));
        gload16(gk, kd + ci*4096 + w*1024);
        int rowv = c >> 3, scol8 = c & 7;
        const char* gv = vgB + (long)rowv * (S_LEN*2) + kt*128
                         + ((scol8*16) ^ ((rowv & 7) << 4));
        gload16(gv, vd + ci*4096 + w*1024);
    }
}

// ---------------------------------------------------------------------------
// Causal GQA flash attention, v12 (round-8 math, co-residency grid) — the
// best-measured variant (r14/r16/r17). r18's V-from-global reverted.
// ---------------------------------------------------------------------------
__global__ __launch_bounds__(256, 2) void attn_kernel(
        const short* __restrict__ qg, const short* __restrict__ kg,
        const short* __restrict__ vtg, short* __restrict__ ctx)
{
    const int bx = blockIdx.x;       // 0..511
    const int h  = bx & 31;          // head
    const int slot = bx >> 5;        // 0..15
    const int qb = (slot < 8) ? slot : 23 - slot;   // complementary pairing
    const int kvh = h >> 2;          // GQA: rep=4
    const int t = threadIdx.x, w = t >> 6, l = t & 63, g = l >> 4, q16 = l & 15;

    __shared__ char Kl[2][16384];    // [kv64][d128] bf16, swizzled
    __shared__ char Vl[2][16384];    // [d128][kv64] bf16, swizzled
    __shared__ short Pl[4][32 * 64]; // per-wave P[32 q][64 kv], swizzled

    const float scale = 0.08838834764831845f;  // 1/sqrt(128)
    const char* kgB = (const char*)kg + (long)kvh * DH * 2;
    const char* vgB = (const char*)vtg + (long)kvh * DH * (long)S_LEN * 2;

    const int nt = 2 * qb + 2;               // kv-tiles of 64
    int qrow[2];
    qrow[0] = qb*128 + w*32 + q16;
    qrow[1] = qrow[0] + 16;

    // Q B-frags for both subtiles (regs for whole block)
    s16x8 qf[2][4];
#pragma unroll
    for (int s = 0; s < 2; ++s) {
        const short* qptr = qg + ((long)qrow[s] * NH + h) * DH;
#pragma unroll
        for (int dk = 0; dk < 4; ++dk)
            qf[s][dk] = *(const s16x8*)(qptr + dk*32 + g*8);
    }

    f32x4 oacc[2][8] = {};
    float m_run[2] = {-1e30f, -1e30f}, l_run[2] = {0.f, 0.f};

    stage_kv(kgB, vgB, 0, t, Kl[0], Vl[0]);
    __syncthreads();   // drain vmcnt -> buf0 ready

    for (int kt = 0; kt < nt; ++kt) {
        const int b = kt & 1;
        if (kt + 1 < nt)   // prefetch next tile into other buffer (async)
            stage_kv(kgB, vgB, kt + 1, t, Kl[b ^ 1], Vl[b ^ 1]);
        const char* kb = Kl[b];
        const char* vbb = Vl[b];

        // ---- QK^T swapped: S^T[kv][q] = K * Q^T; K-frags serve both s
        f32x4 sacc[2][4] = {};
        __builtin_amdgcn_s_setprio(1);
#pragma unroll
        for (int m = 0; m < 4; ++m) {
            int kvr = m*16 + q16;
            s16x8 af[4];
#pragma unroll
            for (int dk = 0; dk < 4; ++dk) {
                int byte = (kvr*256 + (dk*32 + g*8)*2) ^ ((kvr & 7) << 4);
                af[dk] = *(const s16x8*)(kb + byte);
            }
#pragma unroll
            for (int s = 0; s < 2; ++s)
#pragma unroll
                for (int dk = 0; dk < 4; ++dk)
                    sacc[s][m] = __builtin_amdgcn_mfma_f32_16x16x32_bf16(
                            af[dk], qf[s][dk], sacc[s][m], 0,0,0);
        }
        __builtin_amdgcn_s_setprio(0);

        // ---- online softmax; lane owns q-columns qrow[0], qrow[1] ----
        const bool diag = (kt >= 2*qb);      // last two tiles straddle diag
        float mx[2];
#pragma unroll
        for (int s = 0; s < 2; ++s) {
            mx[s] = -1e30f;
#pragma unroll
            for (int m = 0; m < 4; ++m)
#pragma unroll
                for (int r = 0; r < 4; ++r) {
                    float x = sacc[s][m][r] * scale;
                    if (diag) {
                        int kv = kt*64 + m*16 + g*4 + r;
                        if (kv > qrow[s]) x = -1e30f;
                    }
                    sacc[s][m][r] = x;
                    mx[s] = fmaxf(mx[s], x);
                }
            mx[s] = fmaxf(mx[s], __shfl_xor(mx[s], 16));
            mx[s] = fmaxf(mx[s], __shfl_xor(mx[s], 32));
        }
        // defer-max: only rescale when max grew by > 8 somewhere (T13)
        if (__any((mx[0] > m_run[0] + 8.f) || (mx[1] > m_run[1] + 8.f))) {
#pragma unroll
            for (int s = 0; s < 2; ++s) {
                float m_new = fmaxf(m_run[s], mx[s]);
                float corr = __expf(m_run[s] - m_new);
                l_run[s] *= corr;
                m_run[s] = m_new;
                float rf[4];
#pragma unroll
                for (int r = 0; r < 4; ++r)
                    rf[r] = __shfl(corr, (g << 4) | (g*4 + r));
#pragma unroll
                for (int nf = 0; nf < 8; ++nf)
#pragma unroll
                    for (int r = 0; r < 4; ++r) oacc[s][nf][r] *= rf[r];
            }
        }
        // exp + pack to bf16 + LDS write (P bounded by e^8 when deferred)
#pragma unroll
        for (int s = 0; s < 2; ++s) {
            float psum = 0.f;
#pragma unroll
            for (int m = 0; m < 4; ++m) {
                s16x4 pk;
#pragma unroll
                for (int r = 0; r < 4; ++r) {
                    float e = __expf(sacc[s][m][r] - m_run[s]);
                    psum += e;
                    pk[r] = f2bf(e);
                }
                int byte = ((s*16 + q16)*128 + (m*16 + g*4)*2) ^ ((q16 & 7) << 4);
                *(s16x4*)((char*)&Pl[w][0] + byte) = pk;
            }
            psum += __shfl_xor(psum, 16);
            psum += __shfl_xor(psum, 32);
            l_run[s] += psum;
        }

        // ---- PV: O[q][d] += P[q][kv] * V[kv][d]; V-frags serve both s
        __builtin_amdgcn_s_setprio(1);
#pragma unroll
        for (int ks = 0; ks < 2; ++ks) {
            s16x8 pa[2];
#pragma unroll
            for (int s = 0; s < 2; ++s) {
                int pbyte = ((s*16 + q16)*128 + (ks*32 + g*8)*2) ^ ((q16 & 7) << 4);
                pa[s] = *(const s16x8*)((const char*)&Pl[w][0] + pbyte);
            }
#pragma unroll
            for (int nf = 0; nf < 8; ++nf) {
                int drow = nf*16 + q16;
                int vbyte = (drow*128 + (ks*32 + g*8)*2) ^ ((drow & 7) << 4);
                s16x8 vbf = *(const s16x8*)(vbb + vbyte);
#pragma unroll
                for (int s = 0; s < 2; ++s)
                    oacc[s][nf] = __builtin_amdgcn_mfma_f32_16x16x32_bf16(
                            pa[s], vbf, oacc[s][nf], 0,0,0);
            }
        }
        __builtin_amdgcn_s_setprio(0);
        __syncthreads();   // tile done; prefetched buffer complete
    }

    // ---- epilogue: divide by l, write ctx[row][h*128 + d] bf16 ----
#pragma unroll
    for (int s = 0; s < 2; ++s) {
        float lr[4];
#pragma unroll
        for (int r = 0; r < 4; ++r)
            lr[r] = __shfl(l_run[s], (g << 4) | (g*4 + r));
#pragma unroll
        for (int nf = 0; nf < 8; ++nf)
#pragma unroll
            for (int r = 0; r < 4; ++r) {
                int row = qb*128 + w*32 + s*16 + g*4 + r;
                int col = h*DH + nf*16 + q16;
                float val = oacc[s][nf][r] / lr[r];
                ctx[(long)row * (NH*DH) + col] = f2bf(val);
            }
    }
}

// ---------------------------------------------------------------------------
// Workspace layout (race-free, peak 111 MB):
//   [0,16)    hsb (gemm1 A)           -> ctxb (attn out) after gemm1
//   [16,67)   wqkvb (gemm1 B, 50.3MB) -> wob (32MB) after gemm1
//   [48,52)   vtbuf (4MB, written after gemm1)
//   [67,91)   qkvb (gemm1 bf16 out, 24MB)
//   [91,107)  qbuf (16MB)
//   [107,111) kbuf (4MB)
// ---------------------------------------------------------------------------
extern "C" void kernel_launch(void* const* d_in, const int* in_sizes, int n_in,
                              void* d_out, int out_size, void* d_ws, size_t ws_size,
                              hipStream_t stream)
{
    const int*   positions = (const int*)  d_in[0];
    const float* hs        = (const float*)d_in[1];
    const float* wqkv      = (const float*)d_in[2];
    const float* wo        = (const float*)d_in[3];
    const float* gq        = (const float*)d_in[4];
    const float* gk        = (const float*)d_in[5];
    float* out = (float*)d_out;
    char* ws = (char*)d_ws;

    const size_t MB = 1ull << 20;
    short* hsb   = (short*)(ws);
    short* ctxb  = (short*)(ws);
    short* wqkvb = (short*)(ws + 16*MB);
    short* wob   = (short*)(ws + 16*MB);
    short* vtbuf = (short*)(ws + 48*MB);
    short* qkvb  = (short*)(ws + 67*MB);
    short* qbuf  = (short*)(ws + 91*MB);
    short* kbuf  = (short*)(ws + 107*MB);

    (void)in_sizes; (void)n_in; (void)out_size; (void)ws_size;

    convert_hs_wqkv<<<2048, 256, 0, stream>>>(
            hs, hsb, (long)S_LEN * HID,
            wqkv, wqkvb, (long)NQKV * HID);
    gemm192<short><<<dim3(NQKV/192, S_LEN/128), 256, 0, stream>>>(
            hsb, wqkvb, qkvb, S_LEN, NQKV, HID);
    post_gemm1_fused<<<12800, 256, 0, stream>>>(
            wo, wob, qkvb, positions, gq, gk, qbuf, kbuf, vtbuf);
    attn_kernel<<<dim3(512), 256, 0, stream>>>(qbuf, kbuf, vtbuf, ctxb);
    gemm_bt<float><<<dim3(HID/128, S_LEN/128), 512, 0, stream>>>(
            ctxb, wob, out, S_LEN, HID, HID);
}